// Round 1
// 203.794 us; speedup vs baseline: 1.0491x; 1.0491x over previous
//
#include <hip/hip_runtime.h>
#include <math.h>

#define NUM_EMB 1024
#define EMB_DIM 256
#define N_ROWS  65536
#define HW      1024
#define QUANT_OFF 1
#define IDX_OFF   (1 + 16777216)
#define LDA 264   // halfs per A-row in LDS: 528B row stride -> bank stride 4, conflict-free r/w

typedef unsigned int uint;
typedef _Float16 f16x8 __attribute__((ext_vector_type(8)));
typedef float    f32x4 __attribute__((ext_vector_type(4)));

__device__ __forceinline__ uint umin2(uint a, uint b) { return a < b ? a : b; }
__device__ __forceinline__ uint umax2(uint a, uint b) { return a > b ? a : b; }

// median of 3 == 2nd-largest of 3; single VALU op on gfx9+
__device__ __forceinline__ uint umed3(uint a, uint b, uint c) {
  uint d;
  asm("v_med3_u32 %0, %1, %2, %3" : "=v"(d) : "v"(a), "v"(b), "v"(c));
  return d;
}

__device__ __forceinline__ void load_lds16(const _Float16* g, _Float16* l) {
  __builtin_amdgcn_global_load_lds(
      (const __attribute__((address_space(1))) unsigned int*)g,
      (__attribute__((address_space(3))) unsigned int*)l, 16, 0, 0);
}

// ---- kernel 1: normalize codebook -> wn (f32), wh2 (f16, MFMA-B-swizzled), rinv (f64) ----
// wh2 halfs layout: [chunk(4)][ks(8)][q(4)][code-in-chunk(256)][e(8)], d = ks*32+q*8+e.
__global__ __launch_bounds__(256)
void k_norm_w(const float* __restrict__ w, float* __restrict__ wn,
              _Float16* __restrict__ wh2, double* __restrict__ rinv) {
  const int k = blockIdx.x, t = threadIdx.x;
  const float v = w[(size_t)k * EMB_DIM + t];
  double s = (double)v * (double)v;
  for (int o = 32; o; o >>= 1) s += __shfl_down(s, o);
  __shared__ double ps[4];
  if ((t & 63) == 0) ps[t >> 6] = s;
  __syncthreads();
  const double tot = ps[0] + ps[1] + ps[2] + ps[3];
  const float nv = v / fmaxf((float)sqrt(tot), 1e-12f);
  wn[(size_t)k * EMB_DIM + t] = nv;
  const int chunk = k >> 8, cc = k & 255;
  const int ks = t >> 5, q = (t >> 3) & 3, e = t & 7;
  wh2[(size_t)chunk * 65536 + ks * 8192 + q * 2048 + cc * 8 + e] = (_Float16)nv;
  if (t == 0) rinv[k] = 1.0 / fmax(sqrt(tot), 1e-12);
}

// ---- kernel 2: fp16 MFMA GEMM (B via async global_load_lds, double-buffered) + top-4 ----
// 1024 blocks x 256 thr. 64 rows/block; 4 chunks of 256 codes (wave w owns 64);
// per chunk: 8 ks-steps of K=32. B-tile 16 KB staged async into the OTHER buffer while
// computing the current one: ONE barrier per step, stage latency hidden under ds_read+MFMA.
__global__ __launch_bounds__(256)
void k_pass1(const float* __restrict__ x, const _Float16* __restrict__ wh2,
             uint* __restrict__ cand) {
  __shared__ __align__(16) _Float16 As[64 * LDA];   // 33792 B
  __shared__ __align__(16) _Float16 Bs[2][8192];    // 2 x 16384 B: [q(4)][code(256)][8]
  const int t = threadIdx.x;
  const int blk = blockIdx.x;
  const int b = blk >> 4;
  const int hw0 = (blk & 15) * 64;

  // stage B step 0 into buffer 0 (async; drained by the prologue barrier)
  {
    const _Float16* slab = wh2 + (size_t)t * 8;
    _Float16* dst = &Bs[0][t * 8];
#pragma unroll
    for (int i = 0; i < 4; ++i)
      load_lds16(slab + i * 2048, dst + i * 2048);
  }

  // stage A: x[b, d, hw0+r] f32 -> As[r][d] f16, packed 8 d's per ds_write_b128
  {
    const int lhw = t & 63;   // row
    const int ph = t >> 6;    // d-range selector: 64 d's per thread
    const float* xb = x + (size_t)b * (EMB_DIM * HW) + hw0 + lhw;
#pragma unroll
    for (int jp = 0; jp < 8; ++jp) {
      const int d0 = ph * 64 + jp * 8;
      f16x8 v;
#pragma unroll
      for (int e = 0; e < 8; ++e)
        v[e] = (_Float16)xb[(size_t)(d0 + e) * HW];
      *(f16x8*)&As[lhw * LDA + d0] = v;
    }
  }

  const int lane = t & 63;
  const int q = lane >> 4;
  const int l15 = lane & 15;
  const int w = t >> 6;

  uint t1[16], t2[16];
#pragma unroll
  for (int i = 0; i < 16; ++i) { t1[i] = 0u; t2[i] = 0u; }

  __syncthreads();   // A-writes + B step-0 stage complete

  int cur = 0;
  for (int c4 = 0; c4 < 4; ++c4) {
    f32x4 acc[4][4];
#pragma unroll
    for (int rt = 0; rt < 4; ++rt)
#pragma unroll
      for (int ct = 0; ct < 4; ++ct) acc[rt][ct] = (f32x4)0.f;

#pragma unroll 1
    for (int ks = 0; ks < 8; ++ks) {
      const int s = c4 * 8 + ks;
      // issue next step's stage into the other buffer FIRST (overlaps with compute)
      if (s < 31) {
        const int sn = s + 1;
        const _Float16* slab = wh2 + (size_t)(sn >> 3) * 65536 + (sn & 7) * 8192 + t * 8;
        _Float16* dst = &Bs[cur ^ 1][t * 8];
#pragma unroll
        for (int i = 0; i < 4; ++i)
          load_lds16(slab + i * 2048, dst + i * 2048);
      }

      const f16x8 a0 = *(const f16x8*)&As[(0 * 16 + l15) * LDA + ks * 32 + q * 8];
      const f16x8 a1 = *(const f16x8*)&As[(1 * 16 + l15) * LDA + ks * 32 + q * 8];
      const f16x8 a2 = *(const f16x8*)&As[(2 * 16 + l15) * LDA + ks * 32 + q * 8];
      const f16x8 a3 = *(const f16x8*)&As[(3 * 16 + l15) * LDA + ks * 32 + q * 8];
      const f16x8 b0 = *(const f16x8*)&Bs[cur][q * 2048 + (w * 64 +  0 + l15) * 8];
      const f16x8 b1 = *(const f16x8*)&Bs[cur][q * 2048 + (w * 64 + 16 + l15) * 8];
      const f16x8 b2 = *(const f16x8*)&Bs[cur][q * 2048 + (w * 64 + 32 + l15) * 8];
      const f16x8 b3 = *(const f16x8*)&Bs[cur][q * 2048 + (w * 64 + 48 + l15) * 8];
      acc[0][0] = __builtin_amdgcn_mfma_f32_16x16x32_f16(a0, b0, acc[0][0], 0, 0, 0);
      acc[1][0] = __builtin_amdgcn_mfma_f32_16x16x32_f16(a1, b0, acc[1][0], 0, 0, 0);
      acc[2][0] = __builtin_amdgcn_mfma_f32_16x16x32_f16(a2, b0, acc[2][0], 0, 0, 0);
      acc[3][0] = __builtin_amdgcn_mfma_f32_16x16x32_f16(a3, b0, acc[3][0], 0, 0, 0);
      acc[0][1] = __builtin_amdgcn_mfma_f32_16x16x32_f16(a0, b1, acc[0][1], 0, 0, 0);
      acc[1][1] = __builtin_amdgcn_mfma_f32_16x16x32_f16(a1, b1, acc[1][1], 0, 0, 0);
      acc[2][1] = __builtin_amdgcn_mfma_f32_16x16x32_f16(a2, b1, acc[2][1], 0, 0, 0);
      acc[3][1] = __builtin_amdgcn_mfma_f32_16x16x32_f16(a3, b1, acc[3][1], 0, 0, 0);
      acc[0][2] = __builtin_amdgcn_mfma_f32_16x16x32_f16(a0, b2, acc[0][2], 0, 0, 0);
      acc[1][2] = __builtin_amdgcn_mfma_f32_16x16x32_f16(a1, b2, acc[1][2], 0, 0, 0);
      acc[2][2] = __builtin_amdgcn_mfma_f32_16x16x32_f16(a2, b2, acc[2][2], 0, 0, 0);
      acc[3][2] = __builtin_amdgcn_mfma_f32_16x16x32_f16(a3, b2, acc[3][2], 0, 0, 0);
      acc[0][3] = __builtin_amdgcn_mfma_f32_16x16x32_f16(a0, b3, acc[0][3], 0, 0, 0);
      acc[1][3] = __builtin_amdgcn_mfma_f32_16x16x32_f16(a1, b3, acc[1][3], 0, 0, 0);
      acc[2][3] = __builtin_amdgcn_mfma_f32_16x16x32_f16(a2, b3, acc[2][3], 0, 0, 0);
      acc[3][3] = __builtin_amdgcn_mfma_f32_16x16x32_f16(a3, b3, acc[3][3], 0, 0, 0);

      __syncthreads();   // drains vmcnt(0): next buffer staged; all reads of Bs[cur] done
      cur ^= 1;
    }

    // merge into per-(lane,slot) top-2 packed keys (score hi-bits | idx)
#pragma unroll
    for (int ct = 0; ct < 4; ++ct) {
      const uint idxv = (uint)(c4 * 256 + w * 64 + ct * 16 + l15);
#pragma unroll
      for (int rt = 0; rt < 4; ++rt)
#pragma unroll
        for (int r = 0; r < 4; ++r) {
          const float v = fmaxf(acc[rt][ct][r], 0.0f);
          const uint key = (__float_as_uint(v) & 0xFFFFFC00u) | idxv;
          const int slot = rt * 4 + r;
          t2[slot] = umed3(key, t1[slot], t2[slot]);   // 2nd-largest of {key,t1,t2}
          t1[slot] = umax2(key, t1[slot]);
        }
    }
  }

  // ---- block-level per-row top-4 (reuse A LDS as key scratch) ----
  __syncthreads();
  uint* keys = (uint*)As;   // [64 rows][128 keys] = 32 KB
#pragma unroll
  for (int slot = 0; slot < 16; ++slot) {
    const int rt = slot >> 2, r = slot & 3;
    const int row = rt * 16 + q * 4 + r;
    const int col = w * 32 + l15 * 2;
    keys[row * 128 + col] = t1[slot];
    keys[row * 128 + col + 1] = t2[slot];
  }
  __syncthreads();
  {
    const int row = t >> 2, seg = t & 3;
    uint s1 = 0, s2 = 0;
#pragma unroll
    for (int i = 0; i < 8; ++i) {
      const int ii = (i + t) & 7;
      const uint4 k4 = *(const uint4*)&keys[row * 128 + seg * 32 + ii * 4];
      const uint kk[4] = {k4.x, k4.y, k4.z, k4.w};
#pragma unroll
      for (int e = 0; e < 4; ++e) {
        s2 = umed3(kk[e], s1, s2);
        s1 = umax2(kk[e], s1);
      }
    }
    __syncthreads();
    keys[t * 2] = s1;
    keys[t * 2 + 1] = s2;
  }
  __syncthreads();
  if (t < 64) {
    uint c0 = 0, c1 = 0, c2 = 0, c3 = 0;
#pragma unroll
    for (int i = 0; i < 8; ++i) {
      const uint k = keys[t * 8 + i];
      const uint n0 = umin2(c0, k); c0 = umax2(c0, k);
      const uint n1 = umin2(c1, n0); c1 = umax2(c1, n0);
      const uint n2 = umin2(c2, n1); c2 = umax2(c2, n1);
      c3 = umax2(c3, n2);
    }
    uint4 o; o.x = c0; o.y = c1; o.z = c2; o.w = c3;
    *(uint4*)&cand[(size_t)(blk * 64 + t) * 4] = o;
  }
}

// ------- kernel 3: fp64 recheck (rinv precomputed), idx + loss + quant -------
// 2048 blocks x 256 thr; 32 rows/block; 8 lanes per row.
#define XSTR 257
__global__ __launch_bounds__(256)
void k_finish(const float* __restrict__ x, const float* __restrict__ w,
              const float* __restrict__ wn, const double* __restrict__ rinv,
              const uint* __restrict__ cand, float* __restrict__ out) {
  __shared__ float smem[256 * 33];     // phase1: xs[32][257]; phase2: qs[256][33]
  __shared__ double lsum[4];
  const int t = threadIdx.x;
  const int blk = blockIdx.x;
  const int b = blk >> 5;
  const int hw0 = (blk & 31) * 32;

  // stage x tile [32 rows][256 d]
  {
    const int r = t & 31, dp = t >> 5;
    const float* xb = x + (size_t)b * (EMB_DIM * HW) + hw0 + r;
#pragma unroll
    for (int j = 0; j < 32; ++j) {
      const int d = dp * 32 + j;
      smem[r * XSTR + d] = xb[(size_t)d * HW];
    }
  }
  __syncthreads();

  const int row = t >> 3;
  const int li = t & 7;
  const int n0 = blk * 32 + row;
  const uint4 ck = *(const uint4*)&cand[(size_t)n0 * 4];
  const uint cv[4] = {ck.x, ck.y, ck.z, ck.w};

  float xf[32];
#pragma unroll
  for (int k = 0; k < 8; ++k)
#pragma unroll
    for (int e = 0; e < 4; ++e)
      xf[k * 4 + e] = smem[row * XSTR + k * 32 + li * 4 + e];
  __syncthreads();   // smem free for qs reuse

  double sxx = 0.0;
#pragma unroll
  for (int i = 0; i < 32; ++i) sxx = fma((double)xf[i], (double)xf[i], sxx);

  double sj[4];
#pragma unroll
  for (int j = 0; j < 4; ++j) {
    const int c = (int)(cv[j] & 1023u);
    const float* wr = w + (size_t)c * EMB_DIM;
    double s = 0.0;
#pragma unroll
    for (int k = 0; k < 8; ++k) {
      const float4 w4 = *(const float4*)&wr[k * 32 + li * 4];
      const float wv[4] = {w4.x, w4.y, w4.z, w4.w};
#pragma unroll
      for (int e = 0; e < 4; ++e)
        s = fma((double)xf[k * 4 + e], (double)wv[e], s);
    }
    sj[j] = s;
  }

#pragma unroll
  for (int o = 4; o; o >>= 1) {
    sxx += __shfl_down(sxx, o);
#pragma unroll
    for (int j = 0; j < 4; ++j) sj[j] += __shfl_down(sj[j], o);
  }

  double dmin = 0.0;
  int cw = 0;
  if (li == 0) {
    double qbest = -1e300; cw = 1 << 30;
#pragma unroll
    for (int j = 0; j < 4; ++j) {
      const int c = (int)(cv[j] & 1023u);
      const double qj = sj[j] * rinv[c];
      if (qj > qbest || (qj == qbest && c < cw)) { qbest = qj; cw = c; }
    }
    dmin = 2.0 - 2.0 * qbest / fmax(sqrt(sxx), 1e-12);
    out[IDX_OFF + n0] = (float)cw;
  }
  cw = __shfl(cw, (t & 63) & ~7);

  double v = dmin;
  v += __shfl_down(v, 32);
  v += __shfl_down(v, 16);
  v += __shfl_down(v, 8);
  if ((t & 63) == 0) lsum[t >> 6] = v;
  __syncthreads();
  if (t == 0)
    atomicAdd(out, (float)(1.25 * (lsum[0] + lsum[1] + lsum[2] + lsum[3]) / 16777216.0));

  // quant: gather wn[cw] (128B/row) -> qs[d][row(32)+pad] -> float4 coalesced stores
  {
    const float* wr = wn + (size_t)cw * EMB_DIM;
#pragma unroll
    for (int k = 0; k < 8; ++k) {
      const int d0 = k * 32 + li * 4;
      const float4 w4 = *(const float4*)&wr[d0];
      smem[(d0 + 0) * 33 + row] = w4.x;
      smem[(d0 + 1) * 33 + row] = w4.y;
      smem[(d0 + 2) * 33 + row] = w4.z;
      smem[(d0 + 3) * 33 + row] = w4.w;
    }
  }
  __syncthreads();
  {
    const int hw4 = (t & 7) * 4, dbase = t >> 3;   // 32 d-groups of 8
    float* qout = out + QUANT_OFF + (size_t)b * (EMB_DIM * HW) + hw0;
#pragma unroll
    for (int jj = 0; jj < 8; ++jj) {
      const int d = jj * 32 + dbase;
      float4 v4;
      v4.x = smem[d * 33 + hw4 + 0];
      v4.y = smem[d * 33 + hw4 + 1];
      v4.z = smem[d * 33 + hw4 + 2];
      v4.w = smem[d * 33 + hw4 + 3];
      *(float4*)&qout[(size_t)d * HW + hw4] = v4;
    }
  }
}

extern "C" void kernel_launch(void* const* d_in, const int* in_sizes, int n_in,
                              void* d_out, int out_size, void* d_ws, size_t ws_size,
                              hipStream_t stream) {
  const float* x = (const float*)d_in[0];   // [64,256,32,32]
  const float* w = (const float*)d_in[1];   // [1024,256]
  float* out = (float*)d_out;               // [1 + 16777216 + 65536] f32

  char* ws = (char*)d_ws;
  float*     wn   = (float*)ws;                                // 1 MB
  _Float16*  wh2  = (_Float16*)(ws + 1048576);                 // 512 KB (swizzled)
  double*    rinv = (double*)(ws + 1048576 + 524288);          // 8 KB
  uint*      cand = (uint*)(ws + 1048576 + 524288 + 8192);     // 1 MB

  hipMemsetAsync(d_out, 0, sizeof(float), stream);   // zero loss accumulator
  hipLaunchKernelGGL(k_norm_w, dim3(NUM_EMB), dim3(256), 0, stream, w, wn, wh2, rinv);
  hipLaunchKernelGGL(k_pass1, dim3(N_ROWS / 64), dim3(256), 0, stream, x, wh2, cand);
  hipLaunchKernelGGL(k_finish, dim3(N_ROWS / 32), dim3(256), 0, stream, x, w, wn, rinv, cand, out);
}

// Round 2
// 195.587 us; speedup vs baseline: 1.0931x; 1.0420x over previous
//
#include <hip/hip_runtime.h>
#include <math.h>

#define NUM_EMB 1024
#define EMB_DIM 256
#define N_ROWS  65536
#define HW      1024
#define QUANT_OFF 1
#define IDX_OFF   (1 + 16777216)
#define LDA 264   // halfs per A-row in LDS: 528B row stride -> even 8-lane/slot b128 access

typedef unsigned int uint;
typedef _Float16 f16x8 __attribute__((ext_vector_type(8)));
typedef float    f32x4 __attribute__((ext_vector_type(4)));

__device__ __forceinline__ uint umin2(uint a, uint b) { return a < b ? a : b; }
__device__ __forceinline__ uint umax2(uint a, uint b) { return a > b ? a : b; }

// median of 3 == 2nd-largest of 3; single VALU op on gfx9+
__device__ __forceinline__ uint umed3(uint a, uint b, uint c) {
  uint d;
  asm("v_med3_u32 %0, %1, %2, %3" : "=v"(d) : "v"(a), "v"(b), "v"(c));
  return d;
}

// ---- kernel 1: normalize codebook -> wn (f32), wh2 (f16, MFMA-B-swizzled), rinv (f64) ----
// wh2 halfs layout: [chunk(4)][ks(8)][q(4)][code-in-chunk(256)][e(8)], d = ks*32+q*8+e.
__global__ __launch_bounds__(256)
void k_norm_w(const float* __restrict__ w, float* __restrict__ wn,
              _Float16* __restrict__ wh2, double* __restrict__ rinv) {
  const int k = blockIdx.x, t = threadIdx.x;
  const float v = w[(size_t)k * EMB_DIM + t];
  double s = (double)v * (double)v;
  for (int o = 32; o; o >>= 1) s += __shfl_down(s, o);
  __shared__ double ps[4];
  if ((t & 63) == 0) ps[t >> 6] = s;
  __syncthreads();
  const double tot = ps[0] + ps[1] + ps[2] + ps[3];
  const float nv = v / fmaxf((float)sqrt(tot), 1e-12f);
  wn[(size_t)k * EMB_DIM + t] = nv;
  const int chunk = k >> 8, cc = k & 255;
  const int ks = t >> 5, q = (t >> 3) & 3, e = t & 7;
  wh2[(size_t)chunk * 65536 + ks * 8192 + q * 2048 + cc * 8 + e] = (_Float16)nv;
  if (t == 0) rinv[k] = 1.0 / fmax(sqrt(tot), 1e-12);
}

// ---- kernel 2: fp16 MFMA GEMM, A-in-registers, B streamed L2->VGPR, no main-loop barriers ----
// 2048 blocks x 256 thr. 32 rows/block; 4 waves each own 64 codes per chunk; 4 chunks x 8 K-steps.
// A frags (64 VGPR) loaded once from LDS; B frags double-buffered from global (L2-resident wh2).
__global__ __launch_bounds__(256, 2)
void k_pass1(const float* __restrict__ x, const _Float16* __restrict__ wh2,
             uint* __restrict__ cand) {
  __shared__ __align__(16) _Float16 As[32 * LDA];   // 16896 B; reused as key scratch later
  const int t = threadIdx.x;
  const int blk = blockIdx.x;
  const int b = blk >> 5;
  const int hw0 = (blk & 31) * 32;

  const int lane = t & 63;
  const int q = lane >> 4;
  const int l15 = lane & 15;
  const int w = t >> 6;

  // per-lane B element offsets (halfs) within a ks-slab of wh2
  const int bvo0 = q * 2048 + (w * 64 +  0 + l15) * 8;
  const int bvo1 = q * 2048 + (w * 64 + 16 + l15) * 8;
  const int bvo2 = q * 2048 + (w * 64 + 32 + l15) * 8;
  const int bvo3 = q * 2048 + (w * 64 + 48 + l15) * 8;

#define LOADB(buf, cc, kk)                                            \
  { const _Float16* ksb_ = wh2 + (size_t)((cc) * 8 + (kk)) * 8192;    \
    buf[0] = *(const f16x8*)&ksb_[bvo0];                              \
    buf[1] = *(const f16x8*)&ksb_[bvo1];                              \
    buf[2] = *(const f16x8*)&ksb_[bvo2];                              \
    buf[3] = *(const f16x8*)&ksb_[bvo3]; }

  f16x8 bb[2][4];
  LOADB(bb[0], 0, 0);   // prefetch first B step (pure global, overlaps A staging)

  // stage A: x[b, d, hw0+r] f32 -> As[r][d] f16, packed 8 halfs per ds_write_b128
  {
    const int r = t & 31;       // row
    const int dp = t >> 5;      // 8 d-groups of 32
    const float* xb = x + (size_t)b * (EMB_DIM * HW) + hw0 + r;
#pragma unroll
    for (int jp = 0; jp < 4; ++jp) {
      const int d0 = dp * 32 + jp * 8;
      f16x8 v;
#pragma unroll
      for (int e = 0; e < 8; ++e)
        v[e] = (_Float16)xb[(size_t)(d0 + e) * HW];
      *(f16x8*)&As[r * LDA + d0] = v;
    }
  }
  __syncthreads();   // A tile staged

  // load all A fragments into registers (reused across all 4 chunks)
  f16x8 areg[2][8];
#pragma unroll
  for (int rt = 0; rt < 2; ++rt)
#pragma unroll
    for (int ks = 0; ks < 8; ++ks)
      areg[rt][ks] = *(const f16x8*)&As[(rt * 16 + l15) * LDA + ks * 32 + q * 8];

  uint t1[8], t2[8];
#pragma unroll
  for (int i = 0; i < 8; ++i) { t1[i] = 0u; t2[i] = 0u; }

#pragma unroll
  for (int c4 = 0; c4 < 4; ++c4) {
    f32x4 acc[2][4];
#pragma unroll
    for (int rt = 0; rt < 2; ++rt)
#pragma unroll
      for (int ct = 0; ct < 4; ++ct) acc[rt][ct] = (f32x4)0.f;

#pragma unroll
    for (int ks = 0; ks < 8; ++ks) {
      const int cb = ks & 1, nb = cb ^ 1;
      if (ks < 7) { LOADB(bb[nb], c4, ks + 1); }
      else if (c4 < 3) { LOADB(bb[nb], c4 + 1, 0); }   // cross-chunk prefetch
#pragma unroll
      for (int ct = 0; ct < 4; ++ct) {
        acc[0][ct] = __builtin_amdgcn_mfma_f32_16x16x32_f16(areg[0][ks], bb[cb][ct], acc[0][ct], 0, 0, 0);
        acc[1][ct] = __builtin_amdgcn_mfma_f32_16x16x32_f16(areg[1][ks], bb[cb][ct], acc[1][ct], 0, 0, 0);
      }
    }

    // merge into per-(lane,slot) top-2 packed keys (score hi-bits | idx)
#pragma unroll
    for (int ct = 0; ct < 4; ++ct) {
      const uint idxv = (uint)(c4 * 256 + w * 64 + ct * 16 + l15);
#pragma unroll
      for (int rt = 0; rt < 2; ++rt)
#pragma unroll
        for (int r = 0; r < 4; ++r) {
          const float v = fmaxf(acc[rt][ct][r], 0.0f);
          const uint key = (__float_as_uint(v) & 0xFFFFFC00u) | idxv;
          const int slot = rt * 4 + r;
          t2[slot] = umed3(key, t1[slot], t2[slot]);
          t1[slot] = umax2(key, t1[slot]);
        }
    }
  }
#undef LOADB

  // ---- block-level per-row top-4 (reuse A LDS as key scratch: 32 rows x 128 keys = 16 KB) ----
  __syncthreads();   // all waves done with As (A-reg loads complete)
  uint* keys = (uint*)As;
#pragma unroll
  for (int slot = 0; slot < 8; ++slot) {
    const int rt = slot >> 2, r = slot & 3;
    const int row = rt * 16 + q * 4 + r;
    const int col = w * 32 + l15 * 2;
    keys[row * 128 + col] = t1[slot];
    keys[row * 128 + col + 1] = t2[slot];
  }
  __syncthreads();
  {
    const int row = t >> 3, seg = t & 7;   // 8 threads per row, 16 keys each
    uint s1 = 0, s2 = 0;
#pragma unroll
    for (int i = 0; i < 4; ++i) {
      const int ii = (i + t) & 3;
      const uint4 k4 = *(const uint4*)&keys[row * 128 + seg * 16 + ii * 4];
      const uint kk[4] = {k4.x, k4.y, k4.z, k4.w};
#pragma unroll
      for (int e = 0; e < 4; ++e) {
        s2 = umed3(kk[e], s1, s2);
        s1 = umax2(kk[e], s1);
      }
    }
    __syncthreads();
    keys[t * 2] = s1;
    keys[t * 2 + 1] = s2;
  }
  __syncthreads();
  if (t < 32) {
    uint c0 = 0, c1 = 0, c2 = 0, c3 = 0;
#pragma unroll
    for (int i = 0; i < 16; ++i) {
      const uint k = keys[t * 16 + i];
      const uint n0 = umin2(c0, k); c0 = umax2(c0, k);
      const uint n1 = umin2(c1, n0); c1 = umax2(c1, n0);
      const uint n2 = umin2(c2, n1); c2 = umax2(c2, n1);
      c3 = umax2(c3, n2);
    }
    uint4 o; o.x = c0; o.y = c1; o.z = c2; o.w = c3;
    *(uint4*)&cand[(size_t)(blk * 32 + t) * 4] = o;
  }
}

// ------- kernel 3: fp64 recheck (rinv precomputed), idx + loss + quant -------
// 2048 blocks x 256 thr; 32 rows/block; 8 lanes per row.
#define XSTR 257
__global__ __launch_bounds__(256)
void k_finish(const float* __restrict__ x, const float* __restrict__ w,
              const float* __restrict__ wn, const double* __restrict__ rinv,
              const uint* __restrict__ cand, float* __restrict__ out) {
  __shared__ float smem[256 * 33];     // phase1: xs[32][257]; phase2: qs[256][33]
  __shared__ double lsum[4];
  const int t = threadIdx.x;
  const int blk = blockIdx.x;
  const int b = blk >> 5;
  const int hw0 = (blk & 31) * 32;

  // stage x tile [32 rows][256 d]
  {
    const int r = t & 31, dp = t >> 5;
    const float* xb = x + (size_t)b * (EMB_DIM * HW) + hw0 + r;
#pragma unroll
    for (int j = 0; j < 32; ++j) {
      const int d = dp * 32 + j;
      smem[r * XSTR + d] = xb[(size_t)d * HW];
    }
  }
  __syncthreads();

  const int row = t >> 3;
  const int li = t & 7;
  const int n0 = blk * 32 + row;
  const uint4 ck = *(const uint4*)&cand[(size_t)n0 * 4];
  const uint cv[4] = {ck.x, ck.y, ck.z, ck.w};

  float xf[32];
#pragma unroll
  for (int k = 0; k < 8; ++k)
#pragma unroll
    for (int e = 0; e < 4; ++e)
      xf[k * 4 + e] = smem[row * XSTR + k * 32 + li * 4 + e];
  __syncthreads();   // smem free for qs reuse

  double sxx = 0.0;
#pragma unroll
  for (int i = 0; i < 32; ++i) sxx = fma((double)xf[i], (double)xf[i], sxx);

  double sj[4];
#pragma unroll
  for (int j = 0; j < 4; ++j) {
    const int c = (int)(cv[j] & 1023u);
    const float* wr = w + (size_t)c * EMB_DIM;
    double s = 0.0;
#pragma unroll
    for (int k = 0; k < 8; ++k) {
      const float4 w4 = *(const float4*)&wr[k * 32 + li * 4];
      const float wv[4] = {w4.x, w4.y, w4.z, w4.w};
#pragma unroll
      for (int e = 0; e < 4; ++e)
        s = fma((double)xf[k * 4 + e], (double)wv[e], s);
    }
    sj[j] = s;
  }

#pragma unroll
  for (int o = 4; o; o >>= 1) {
    sxx += __shfl_down(sxx, o);
#pragma unroll
    for (int j = 0; j < 4; ++j) sj[j] += __shfl_down(sj[j], o);
  }

  double dmin = 0.0;
  int cw = 0;
  if (li == 0) {
    double qbest = -1e300; cw = 1 << 30;
#pragma unroll
    for (int j = 0; j < 4; ++j) {
      const int c = (int)(cv[j] & 1023u);
      const double qj = sj[j] * rinv[c];
      if (qj > qbest || (qj == qbest && c < cw)) { qbest = qj; cw = c; }
    }
    dmin = 2.0 - 2.0 * qbest / fmax(sqrt(sxx), 1e-12);
    out[IDX_OFF + n0] = (float)cw;
  }
  cw = __shfl(cw, (t & 63) & ~7);

  double v = dmin;
  v += __shfl_down(v, 32);
  v += __shfl_down(v, 16);
  v += __shfl_down(v, 8);
  if ((t & 63) == 0) lsum[t >> 6] = v;
  __syncthreads();
  if (t == 0)
    atomicAdd(out, (float)(1.25 * (lsum[0] + lsum[1] + lsum[2] + lsum[3]) / 16777216.0));

  // quant: gather wn[cw] (128B/row) -> qs[d][row(32)+pad] -> float4 coalesced stores
  {
    const float* wr = wn + (size_t)cw * EMB_DIM;
#pragma unroll
    for (int k = 0; k < 8; ++k) {
      const int d0 = k * 32 + li * 4;
      const float4 w4 = *(const float4*)&wr[d0];
      smem[(d0 + 0) * 33 + row] = w4.x;
      smem[(d0 + 1) * 33 + row] = w4.y;
      smem[(d0 + 2) * 33 + row] = w4.z;
      smem[(d0 + 3) * 33 + row] = w4.w;
    }
  }
  __syncthreads();
  {
    const int hw4 = (t & 7) * 4, dbase = t >> 3;   // 32 d-groups of 8
    float* qout = out + QUANT_OFF + (size_t)b * (EMB_DIM * HW) + hw0;
#pragma unroll
    for (int jj = 0; jj < 8; ++jj) {
      const int d = jj * 32 + dbase;
      float4 v4;
      v4.x = smem[d * 33 + hw4 + 0];
      v4.y = smem[d * 33 + hw4 + 1];
      v4.z = smem[d * 33 + hw4 + 2];
      v4.w = smem[d * 33 + hw4 + 3];
      *(float4*)&qout[(size_t)d * HW + hw4] = v4;
    }
  }
}

extern "C" void kernel_launch(void* const* d_in, const int* in_sizes, int n_in,
                              void* d_out, int out_size, void* d_ws, size_t ws_size,
                              hipStream_t stream) {
  const float* x = (const float*)d_in[0];   // [64,256,32,32]
  const float* w = (const float*)d_in[1];   // [1024,256]
  float* out = (float*)d_out;               // [1 + 16777216 + 65536] f32

  char* ws = (char*)d_ws;
  float*     wn   = (float*)ws;                                // 1 MB
  _Float16*  wh2  = (_Float16*)(ws + 1048576);                 // 512 KB (swizzled)
  double*    rinv = (double*)(ws + 1048576 + 524288);          // 8 KB
  uint*      cand = (uint*)(ws + 1048576 + 524288 + 8192);     // 1 MB

  hipMemsetAsync(d_out, 0, sizeof(float), stream);   // zero loss accumulator
  hipLaunchKernelGGL(k_norm_w, dim3(NUM_EMB), dim3(256), 0, stream, w, wn, wh2, rinv);
  hipLaunchKernelGGL(k_pass1, dim3(N_ROWS / 32), dim3(256), 0, stream, x, wh2, cand);
  hipLaunchKernelGGL(k_finish, dim3(N_ROWS / 32), dim3(256), 0, stream, x, w, wn, rinv, cand, out);
}

// Round 3
// 185.944 us; speedup vs baseline: 1.1498x; 1.0519x over previous
//
#include <hip/hip_runtime.h>
#include <math.h>

#define NUM_EMB 1024
#define EMB_DIM 256
#define N_ROWS  65536
#define HW      1024
#define QUANT_OFF 1
#define IDX_OFF   (1 + 16777216)
#define LDA 264   // halfs per A-row: 528B stride -> dword stride 132 -> clean 8-round b128 access
#define KSTR 132  // key-scratch row stride in dwords (row-varying bank rotation)

typedef unsigned int uint;
typedef _Float16 f16x8 __attribute__((ext_vector_type(8)));
typedef float    f32x4 __attribute__((ext_vector_type(4)));

__device__ __forceinline__ uint umin2(uint a, uint b) { return a < b ? a : b; }
__device__ __forceinline__ uint umax2(uint a, uint b) { return a > b ? a : b; }

// median of 3 == 2nd-largest of 3; single VALU op on gfx9+
__device__ __forceinline__ uint umed3(uint a, uint b, uint c) {
  uint d;
  asm("v_med3_u32 %0, %1, %2, %3" : "=v"(d) : "v"(a), "v"(b), "v"(c));
  return d;
}

// ---- kernel 1: normalize codebook -> wn (f32), wh2 (f16, MFMA-B-swizzled), rinv (f64) ----
// wh2 halfs layout: [chunk(4)][ks(8)][q(4)][code-in-chunk(256)][e(8)], d = ks*32+q*8+e.
__global__ __launch_bounds__(256)
void k_norm_w(const float* __restrict__ w, float* __restrict__ wn,
              _Float16* __restrict__ wh2, double* __restrict__ rinv) {
  const int k = blockIdx.x, t = threadIdx.x;
  const float v = w[(size_t)k * EMB_DIM + t];
  double s = (double)v * (double)v;
  for (int o = 32; o; o >>= 1) s += __shfl_down(s, o);
  __shared__ double ps[4];
  if ((t & 63) == 0) ps[t >> 6] = s;
  __syncthreads();
  const double tot = ps[0] + ps[1] + ps[2] + ps[3];
  const float nv = v / fmaxf((float)sqrt(tot), 1e-12f);
  wn[(size_t)k * EMB_DIM + t] = nv;
  const int chunk = k >> 8, cc = k & 255;
  const int ks = t >> 5, q = (t >> 3) & 3, e = t & 7;
  wh2[(size_t)chunk * 65536 + ks * 8192 + q * 2048 + cc * 8 + e] = (_Float16)nv;
  if (t == 0) rinv[k] = 1.0 / fmax(sqrt(tot), 1e-12);
}

// ---- kernel 2: 64-row blocks; A in LDS (read per step), B streamed L2->VGPR; no loop barriers ----
// 1024 blocks x 256 thr. Each wave: 4 row-tiles of 16, 64 codes per chunk; 4 chunks x 8 K-steps.
__global__ __launch_bounds__(256, 3)
void k_pass1(const float* __restrict__ x, const _Float16* __restrict__ wh2,
             uint* __restrict__ cand) {
  __shared__ __align__(16) _Float16 As[64 * LDA];   // 33792 B; reused as key scratch later
  const int t = threadIdx.x;
  const int blk = blockIdx.x;
  const int b = blk >> 4;
  const int hw0 = (blk & 15) * 64;

  const int lane = t & 63;
  const int q = lane >> 4;
  const int l15 = lane & 15;
  const int w = t >> 6;

  // per-lane B element offsets (halfs) within a ks-slab of wh2
  const int bvo0 = q * 2048 + (w * 64 +  0 + l15) * 8;
  const int bvo1 = q * 2048 + (w * 64 + 16 + l15) * 8;
  const int bvo2 = q * 2048 + (w * 64 + 32 + l15) * 8;
  const int bvo3 = q * 2048 + (w * 64 + 48 + l15) * 8;

#define LOADB(buf, cc, kk)                                            \
  { const _Float16* ksb_ = wh2 + (size_t)((cc) * 8 + (kk)) * 8192;    \
    buf[0] = *(const f16x8*)&ksb_[bvo0];                              \
    buf[1] = *(const f16x8*)&ksb_[bvo1];                              \
    buf[2] = *(const f16x8*)&ksb_[bvo2];                              \
    buf[3] = *(const f16x8*)&ksb_[bvo3]; }

  f16x8 bb[2][4];
  LOADB(bb[0], 0, 0);   // prefetch first B step (pure global, overlaps A staging)

  // stage A: x[b, d, hw0+r] f32 -> As[r][d] f16, packed 8 halfs per ds_write_b128
  {
    const int r = t & 63;       // row
    const int ph = t >> 6;      // 64 d's per thread
    const float* xb = x + (size_t)b * (EMB_DIM * HW) + hw0 + r;
#pragma unroll
    for (int jp = 0; jp < 8; ++jp) {
      const int d0 = ph * 64 + jp * 8;
      f16x8 v;
#pragma unroll
      for (int e = 0; e < 8; ++e)
        v[e] = (_Float16)xb[(size_t)(d0 + e) * HW];
      *(f16x8*)&As[r * LDA + d0] = v;
    }
  }
  __syncthreads();   // A tile staged

  uint t1[16], t2[16];
#pragma unroll
  for (int i = 0; i < 16; ++i) { t1[i] = 0u; t2[i] = 0u; }

#pragma unroll
  for (int c4 = 0; c4 < 4; ++c4) {
    f32x4 acc[4][4];
#pragma unroll
    for (int rt = 0; rt < 4; ++rt)
#pragma unroll
      for (int ct = 0; ct < 4; ++ct) acc[rt][ct] = (f32x4)0.f;

#pragma unroll
    for (int ks = 0; ks < 8; ++ks) {
      const int cb = ks & 1, nb = cb ^ 1;
      if (ks < 7) { LOADB(bb[nb], c4, ks + 1); }
      else if (c4 < 3) { LOADB(bb[nb], c4 + 1, 0); }   // cross-chunk prefetch

      const f16x8 a0 = *(const f16x8*)&As[(0 * 16 + l15) * LDA + ks * 32 + q * 8];
      const f16x8 a1 = *(const f16x8*)&As[(1 * 16 + l15) * LDA + ks * 32 + q * 8];
      const f16x8 a2 = *(const f16x8*)&As[(2 * 16 + l15) * LDA + ks * 32 + q * 8];
      const f16x8 a3 = *(const f16x8*)&As[(3 * 16 + l15) * LDA + ks * 32 + q * 8];

      __builtin_amdgcn_s_setprio(1);
#pragma unroll
      for (int ct = 0; ct < 4; ++ct) {
        acc[0][ct] = __builtin_amdgcn_mfma_f32_16x16x32_f16(a0, bb[cb][ct], acc[0][ct], 0, 0, 0);
        acc[1][ct] = __builtin_amdgcn_mfma_f32_16x16x32_f16(a1, bb[cb][ct], acc[1][ct], 0, 0, 0);
        acc[2][ct] = __builtin_amdgcn_mfma_f32_16x16x32_f16(a2, bb[cb][ct], acc[2][ct], 0, 0, 0);
        acc[3][ct] = __builtin_amdgcn_mfma_f32_16x16x32_f16(a3, bb[cb][ct], acc[3][ct], 0, 0, 0);
      }
      __builtin_amdgcn_s_setprio(0);
    }

    // merge into per-(lane,slot) top-2 packed keys (score hi-bits | idx)
#pragma unroll
    for (int ct = 0; ct < 4; ++ct) {
      const uint idxv = (uint)(c4 * 256 + w * 64 + ct * 16 + l15);
#pragma unroll
      for (int rt = 0; rt < 4; ++rt)
#pragma unroll
        for (int r = 0; r < 4; ++r) {
          const float v = fmaxf(acc[rt][ct][r], 0.0f);
          const uint key = (__float_as_uint(v) & 0xFFFFFC00u) | idxv;
          const int slot = rt * 4 + r;
          t2[slot] = umed3(key, t1[slot], t2[slot]);
          t1[slot] = umax2(key, t1[slot]);
        }
    }
  }
#undef LOADB

  // ---- block-level per-row top-4 (reuse A LDS as key scratch: 64 rows x KSTR dwords) ----
  __syncthreads();   // all waves done reading As
  uint* keys = (uint*)As;
#pragma unroll
  for (int slot = 0; slot < 16; ++slot) {
    const int rt = slot >> 2, r = slot & 3;
    const int row = rt * 16 + q * 4 + r;
    const int col = w * 32 + l15 * 2;
    keys[row * KSTR + col] = t1[slot];
    keys[row * KSTR + col + 1] = t2[slot];
  }
  __syncthreads();
  {
    const int row = t >> 2, seg = t & 3;   // 4 threads per row, 32 keys each
    uint s1 = 0, s2 = 0;
#pragma unroll
    for (int i = 0; i < 8; ++i) {
      const int ii = (i + t) & 7;
      const uint4 k4 = *(const uint4*)&keys[row * KSTR + seg * 32 + ii * 4];
      const uint kk[4] = {k4.x, k4.y, k4.z, k4.w};
#pragma unroll
      for (int e = 0; e < 4; ++e) {
        s2 = umed3(kk[e], s1, s2);
        s1 = umax2(kk[e], s1);
      }
    }
    __syncthreads();
    keys[t * 2] = s1;
    keys[t * 2 + 1] = s2;
  }
  __syncthreads();
  if (t < 64) {
    uint c0 = 0, c1 = 0, c2 = 0, c3 = 0;
#pragma unroll
    for (int i = 0; i < 8; ++i) {
      const uint k = keys[t * 8 + i];
      const uint n0 = umin2(c0, k); c0 = umax2(c0, k);
      const uint n1 = umin2(c1, n0); c1 = umax2(c1, n0);
      const uint n2 = umin2(c2, n1); c2 = umax2(c2, n1);
      c3 = umax2(c3, n2);
    }
    uint4 o; o.x = c0; o.y = c1; o.z = c2; o.w = c3;
    *(uint4*)&cand[(size_t)(blk * 64 + t) * 4] = o;
  }
}

// ------- kernel 3: fp64 recheck (rinv precomputed), idx + loss + quant -------
// 2048 blocks x 256 thr; 32 rows/block; 8 lanes per row.
#define XSTR 257
__global__ __launch_bounds__(256)
void k_finish(const float* __restrict__ x, const float* __restrict__ w,
              const float* __restrict__ wn, const double* __restrict__ rinv,
              const uint* __restrict__ cand, float* __restrict__ out) {
  __shared__ float smem[256 * 33];     // phase1: xs[32][257]; phase2: qs[256][33]
  __shared__ double lsum[4];
  const int t = threadIdx.x;
  const int blk = blockIdx.x;
  const int b = blk >> 5;
  const int hw0 = (blk & 31) * 32;

  // stage x tile [32 rows][256 d]
  {
    const int r = t & 31, dp = t >> 5;
    const float* xb = x + (size_t)b * (EMB_DIM * HW) + hw0 + r;
#pragma unroll
    for (int j = 0; j < 32; ++j) {
      const int d = dp * 32 + j;
      smem[r * XSTR + d] = xb[(size_t)d * HW];
    }
  }
  __syncthreads();

  const int row = t >> 3;
  const int li = t & 7;
  const int n0 = blk * 32 + row;
  const uint4 ck = *(const uint4*)&cand[(size_t)n0 * 4];
  const uint cv[4] = {ck.x, ck.y, ck.z, ck.w};

  float xf[32];
#pragma unroll
  for (int k = 0; k < 8; ++k)
#pragma unroll
    for (int e = 0; e < 4; ++e)
      xf[k * 4 + e] = smem[row * XSTR + k * 32 + li * 4 + e];
  __syncthreads();   // smem free for qs reuse

  double sxx = 0.0;
#pragma unroll
  for (int i = 0; i < 32; ++i) sxx = fma((double)xf[i], (double)xf[i], sxx);

  double sj[4];
#pragma unroll
  for (int j = 0; j < 4; ++j) {
    const int c = (int)(cv[j] & 1023u);
    const float* wr = w + (size_t)c * EMB_DIM;
    double s = 0.0;
#pragma unroll
    for (int k = 0; k < 8; ++k) {
      const float4 w4 = *(const float4*)&wr[k * 32 + li * 4];
      const float wv[4] = {w4.x, w4.y, w4.z, w4.w};
#pragma unroll
      for (int e = 0; e < 4; ++e)
        s = fma((double)xf[k * 4 + e], (double)wv[e], s);
    }
    sj[j] = s;
  }

#pragma unroll
  for (int o = 4; o; o >>= 1) {
    sxx += __shfl_down(sxx, o);
#pragma unroll
    for (int j = 0; j < 4; ++j) sj[j] += __shfl_down(sj[j], o);
  }

  double dmin = 0.0;
  int cw = 0;
  if (li == 0) {
    double qbest = -1e300; cw = 1 << 30;
#pragma unroll
    for (int j = 0; j < 4; ++j) {
      const int c = (int)(cv[j] & 1023u);
      const double qj = sj[j] * rinv[c];
      if (qj > qbest || (qj == qbest && c < cw)) { qbest = qj; cw = c; }
    }
    dmin = 2.0 - 2.0 * qbest / fmax(sqrt(sxx), 1e-12);
    out[IDX_OFF + n0] = (float)cw;
  }
  cw = __shfl(cw, (t & 63) & ~7);

  double v = dmin;
  v += __shfl_down(v, 32);
  v += __shfl_down(v, 16);
  v += __shfl_down(v, 8);
  if ((t & 63) == 0) lsum[t >> 6] = v;
  __syncthreads();
  if (t == 0)
    atomicAdd(out, (float)(1.25 * (lsum[0] + lsum[1] + lsum[2] + lsum[3]) / 16777216.0));

  // quant: gather wn[cw] (128B/row) -> qs[d][row(32)+pad] -> float4 coalesced stores
  {
    const float* wr = wn + (size_t)cw * EMB_DIM;
#pragma unroll
    for (int k = 0; k < 8; ++k) {
      const int d0 = k * 32 + li * 4;
      const float4 w4 = *(const float4*)&wr[d0];
      smem[(d0 + 0) * 33 + row] = w4.x;
      smem[(d0 + 1) * 33 + row] = w4.y;
      smem[(d0 + 2) * 33 + row] = w4.z;
      smem[(d0 + 3) * 33 + row] = w4.w;
    }
  }
  __syncthreads();
  {
    const int hw4 = (t & 7) * 4, dbase = t >> 3;   // 32 d-groups of 8
    float* qout = out + QUANT_OFF + (size_t)b * (EMB_DIM * HW) + hw0;
#pragma unroll
    for (int jj = 0; jj < 8; ++jj) {
      const int d = jj * 32 + dbase;
      float4 v4;
      v4.x = smem[d * 33 + hw4 + 0];
      v4.y = smem[d * 33 + hw4 + 1];
      v4.z = smem[d * 33 + hw4 + 2];
      v4.w = smem[d * 33 + hw4 + 3];
      *(float4*)&qout[(size_t)d * HW + hw4] = v4;
    }
  }
}

extern "C" void kernel_launch(void* const* d_in, const int* in_sizes, int n_in,
                              void* d_out, int out_size, void* d_ws, size_t ws_size,
                              hipStream_t stream) {
  const float* x = (const float*)d_in[0];   // [64,256,32,32]
  const float* w = (const float*)d_in[1];   // [1024,256]
  float* out = (float*)d_out;               // [1 + 16777216 + 65536] f32

  char* ws = (char*)d_ws;
  float*     wn   = (float*)ws;                                // 1 MB
  _Float16*  wh2  = (_Float16*)(ws + 1048576);                 // 512 KB (swizzled)
  double*    rinv = (double*)(ws + 1048576 + 524288);          // 8 KB
  uint*      cand = (uint*)(ws + 1048576 + 524288 + 8192);     // 1 MB

  hipMemsetAsync(d_out, 0, sizeof(float), stream);   // zero loss accumulator
  hipLaunchKernelGGL(k_norm_w, dim3(NUM_EMB), dim3(256), 0, stream, w, wn, wh2, rinv);
  hipLaunchKernelGGL(k_pass1, dim3(N_ROWS / 64), dim3(256), 0, stream, x, wh2, cand);
  hipLaunchKernelGGL(k_finish, dim3(N_ROWS / 32), dim3(256), 0, stream, x, w, wn, rinv, cand, out);
}

// Round 4
// 185.435 us; speedup vs baseline: 1.1530x; 1.0027x over previous
//
#include <hip/hip_runtime.h>
#include <math.h>

#define NUM_EMB 1024
#define EMB_DIM 256
#define N_ROWS  65536
#define HW      1024
#define QUANT_OFF 1
#define IDX_OFF   (1 + 16777216)
#define LDA 264   // halfs per A-row: 528B stride -> clean 8-round b128 access
#define KSTR 132  // key-scratch row stride in dwords

typedef unsigned int uint;
typedef _Float16 f16x8 __attribute__((ext_vector_type(8)));
typedef float    f32x4 __attribute__((ext_vector_type(4)));

__device__ __forceinline__ uint umin2(uint a, uint b) { return a < b ? a : b; }
__device__ __forceinline__ uint umax2(uint a, uint b) { return a > b ? a : b; }

// median of 3 == 2nd-largest of 3; single VALU op on gfx9+
__device__ __forceinline__ uint umed3(uint a, uint b, uint c) {
  uint d;
  asm("v_med3_u32 %0, %1, %2, %3" : "=v"(d) : "v"(a), "v"(b), "v"(c));
  return d;
}

// ---- kernel 1: normalize codebook -> wn (f32), wh2 (f16, MFMA-B-swizzled), rinv (f64) ----
// wh2 halfs layout: [chunk(4)][ks(8)][q(4)][code-in-chunk(256)][e(8)], d = ks*32+q*8+e.
__global__ __launch_bounds__(256)
void k_norm_w(const float* __restrict__ w, float* __restrict__ wn,
              _Float16* __restrict__ wh2, double* __restrict__ rinv) {
  const int k = blockIdx.x, t = threadIdx.x;
  const float v = w[(size_t)k * EMB_DIM + t];
  double s = (double)v * (double)v;
  for (int o = 32; o; o >>= 1) s += __shfl_down(s, o);
  __shared__ double ps[4];
  if ((t & 63) == 0) ps[t >> 6] = s;
  __syncthreads();
  const double tot = ps[0] + ps[1] + ps[2] + ps[3];
  const float nv = v / fmaxf((float)sqrt(tot), 1e-12f);
  wn[(size_t)k * EMB_DIM + t] = nv;
  const int chunk = k >> 8, cc = k & 255;
  const int ks = t >> 5, q = (t >> 3) & 3, e = t & 7;
  wh2[(size_t)chunk * 65536 + ks * 8192 + q * 2048 + cc * 8 + e] = (_Float16)nv;
  if (t == 0) rinv[k] = 1.0 / fmax(sqrt(tot), 1e-12);
}

// ---- fused kernel: MFMA top-4 + fp64 recheck + loss + quant, one pass over x ----
// 1024 blocks x 256 thr, 64 rows/block. x row-slice kept in f32 registers (xv[64])
// through the MFMA phase; recheck reduces fp64 partials through LDS; quant via
// two 32-row transpose passes reusing the As LDS buffer.
__global__ __launch_bounds__(256, 2)
void k_fused(const float* __restrict__ x, const _Float16* __restrict__ wh2,
             const float* __restrict__ w, const float* __restrict__ wn,
             const double* __restrict__ rinv, float* __restrict__ out) {
  __shared__ __align__(16) _Float16 As[64 * LDA];   // 33792 B; reused: keys / red / qs
  __shared__ uint4 cand_s[64];
  __shared__ int   cw_s[64];
  const int t = threadIdx.x;
  const int blk = blockIdx.x;
  const int b = blk >> 4;
  const int hw0 = (blk & 15) * 64;

  const int lane = t & 63;
  const int q = lane >> 4;
  const int l15 = lane & 15;
  const int w4id = t >> 6;

  // per-lane B element offsets (halfs) within a ks-slab of wh2
  const int bvo0 = q * 2048 + (w4id * 64 +  0 + l15) * 8;
  const int bvo1 = q * 2048 + (w4id * 64 + 16 + l15) * 8;
  const int bvo2 = q * 2048 + (w4id * 64 + 32 + l15) * 8;
  const int bvo3 = q * 2048 + (w4id * 64 + 48 + l15) * 8;

#define LOADB(buf, cc, kk)                                            \
  { const _Float16* ksb_ = wh2 + (size_t)((cc) * 8 + (kk)) * 8192;    \
    buf[0] = *(const f16x8*)&ksb_[bvo0];                              \
    buf[1] = *(const f16x8*)&ksb_[bvo1];                              \
    buf[2] = *(const f16x8*)&ksb_[bvo2];                              \
    buf[3] = *(const f16x8*)&ksb_[bvo3]; }

  f16x8 bb[2][4];
  LOADB(bb[0], 0, 0);   // prefetch first B step (overlaps A staging)

  // stage A: x[b, d, hw0+r] f32 -> As[r][d] f16; KEEP the f32 values in registers
  const int r_own = t & 63;       // row this thread owns for staging & recheck
  const int ph = t >> 6;          // d-range: ph*64 .. ph*64+63
  float xv[64];
  {
    const float* xb = x + (size_t)b * (EMB_DIM * HW) + hw0 + r_own;
#pragma unroll
    for (int jp = 0; jp < 8; ++jp) {
      const int d0 = ph * 64 + jp * 8;
      f16x8 v;
#pragma unroll
      for (int e = 0; e < 8; ++e) {
        const float f = xb[(size_t)(d0 + e) * HW];
        xv[jp * 8 + e] = f;
        v[e] = (_Float16)f;
      }
      *(f16x8*)&As[r_own * LDA + d0] = v;
    }
  }
  __syncthreads();   // A tile staged

  uint t1[16], t2[16];
#pragma unroll
  for (int i = 0; i < 16; ++i) { t1[i] = 0u; t2[i] = 0u; }

#pragma unroll
  for (int c4 = 0; c4 < 4; ++c4) {
    f32x4 acc[4][4];
#pragma unroll
    for (int rt = 0; rt < 4; ++rt)
#pragma unroll
      for (int ct = 0; ct < 4; ++ct) acc[rt][ct] = (f32x4)0.f;

#pragma unroll
    for (int ks = 0; ks < 8; ++ks) {
      const int cb = ks & 1, nb = cb ^ 1;
      if (ks < 7) { LOADB(bb[nb], c4, ks + 1); }
      else if (c4 < 3) { LOADB(bb[nb], c4 + 1, 0); }   // cross-chunk prefetch

      const f16x8 a0 = *(const f16x8*)&As[(0 * 16 + l15) * LDA + ks * 32 + q * 8];
      const f16x8 a1 = *(const f16x8*)&As[(1 * 16 + l15) * LDA + ks * 32 + q * 8];
      const f16x8 a2 = *(const f16x8*)&As[(2 * 16 + l15) * LDA + ks * 32 + q * 8];
      const f16x8 a3 = *(const f16x8*)&As[(3 * 16 + l15) * LDA + ks * 32 + q * 8];

      __builtin_amdgcn_s_setprio(1);
#pragma unroll
      for (int ct = 0; ct < 4; ++ct) {
        acc[0][ct] = __builtin_amdgcn_mfma_f32_16x16x32_f16(a0, bb[cb][ct], acc[0][ct], 0, 0, 0);
        acc[1][ct] = __builtin_amdgcn_mfma_f32_16x16x32_f16(a1, bb[cb][ct], acc[1][ct], 0, 0, 0);
        acc[2][ct] = __builtin_amdgcn_mfma_f32_16x16x32_f16(a2, bb[cb][ct], acc[2][ct], 0, 0, 0);
        acc[3][ct] = __builtin_amdgcn_mfma_f32_16x16x32_f16(a3, bb[cb][ct], acc[3][ct], 0, 0, 0);
      }
      __builtin_amdgcn_s_setprio(0);
    }

    // merge into per-(lane,slot) top-2 packed keys (score hi-bits | idx)
#pragma unroll
    for (int ct = 0; ct < 4; ++ct) {
      const uint idxv = (uint)(c4 * 256 + w4id * 64 + ct * 16 + l15);
#pragma unroll
      for (int rt = 0; rt < 4; ++rt)
#pragma unroll
        for (int r = 0; r < 4; ++r) {
          const float v = fmaxf(acc[rt][ct][r], 0.0f);
          const uint key = (__float_as_uint(v) & 0xFFFFFC00u) | idxv;
          const int slot = rt * 4 + r;
          t2[slot] = umed3(key, t1[slot], t2[slot]);
          t1[slot] = umax2(key, t1[slot]);
        }
    }
  }
#undef LOADB

  // ---- block-level per-row top-4 (reuse A LDS as key scratch: 64 rows x KSTR dwords) ----
  __syncthreads();   // all waves done reading As
  uint* keys = (uint*)As;
#pragma unroll
  for (int slot = 0; slot < 16; ++slot) {
    const int rt = slot >> 2, r = slot & 3;
    const int row = rt * 16 + q * 4 + r;
    const int col = w4id * 32 + l15 * 2;
    keys[row * KSTR + col] = t1[slot];
    keys[row * KSTR + col + 1] = t2[slot];
  }
  __syncthreads();
  {
    const int row = t >> 2, seg = t & 3;   // 4 threads per row, 32 keys each
    uint s1 = 0, s2 = 0;
#pragma unroll
    for (int i = 0; i < 8; ++i) {
      const int ii = (i + t) & 7;
      const uint4 k4 = *(const uint4*)&keys[row * KSTR + seg * 32 + ii * 4];
      const uint kk[4] = {k4.x, k4.y, k4.z, k4.w};
#pragma unroll
      for (int e = 0; e < 4; ++e) {
        s2 = umed3(kk[e], s1, s2);
        s1 = umax2(kk[e], s1);
      }
    }
    __syncthreads();
    keys[t * 2] = s1;
    keys[t * 2 + 1] = s2;
  }
  __syncthreads();
  if (t < 64) {
    uint c0 = 0, c1 = 0, c2 = 0, c3 = 0;
#pragma unroll
    for (int i = 0; i < 8; ++i) {
      const uint k = keys[t * 8 + i];
      const uint n0 = umin2(c0, k); c0 = umax2(c0, k);
      const uint n1 = umin2(c1, n0); c1 = umax2(c1, n0);
      const uint n2 = umin2(c2, n1); c2 = umax2(c2, n1);
      c3 = umax2(c3, n2);
    }
    uint4 o; o.x = c0; o.y = c1; o.z = c2; o.w = c3;
    cand_s[t] = o;
  }
  __syncthreads();

  // ---- fp64 recheck: each thread covers its own (row, 64-d slice) with xv in regs ----
  double* red = (double*)As;   // 256 threads x 5 doubles = 10240 B
  {
    const uint4 ck = cand_s[r_own];
    const uint cv[4] = {ck.x, ck.y, ck.z, ck.w};
    double sxx_p = 0.0;
#pragma unroll
    for (int i = 0; i < 64; ++i) sxx_p = fma((double)xv[i], (double)xv[i], sxx_p);
#pragma unroll
    for (int j = 0; j < 4; ++j) {
      const int c = (int)(cv[j] & 1023u);
      const float* wr = w + (size_t)c * EMB_DIM + ph * 64;
      double s = 0.0;
#pragma unroll
      for (int k = 0; k < 16; ++k) {
        const float4 wv = *(const float4*)&wr[k * 4];
        s = fma((double)xv[k * 4 + 0], (double)wv.x, s);
        s = fma((double)xv[k * 4 + 1], (double)wv.y, s);
        s = fma((double)xv[k * 4 + 2], (double)wv.z, s);
        s = fma((double)xv[k * 4 + 3], (double)wv.w, s);
      }
      red[t * 5 + j] = s;
    }
    red[t * 5 + 4] = sxx_p;
  }
  __syncthreads();

  // ---- per-row decision (wave 0), loss reduce, idx store ----
  if (t < 64) {
    const uint4 ck = cand_s[t];
    const uint cv[4] = {ck.x, ck.y, ck.z, ck.w};
    double sj[4] = {0.0, 0.0, 0.0, 0.0};
    double sxx = 0.0;
#pragma unroll
    for (int p = 0; p < 4; ++p) {
      const int base = (p * 64 + t) * 5;
      sj[0] += red[base + 0];
      sj[1] += red[base + 1];
      sj[2] += red[base + 2];
      sj[3] += red[base + 3];
      sxx   += red[base + 4];
    }
    double qbest = -1e300; int cw = 1 << 30;
#pragma unroll
    for (int j = 0; j < 4; ++j) {
      const int c = (int)(cv[j] & 1023u);
      const double qj = sj[j] * rinv[c];
      if (qj > qbest || (qj == qbest && c < cw)) { qbest = qj; cw = c; }
    }
    const double dmin = 2.0 - 2.0 * qbest / fmax(sqrt(sxx), 1e-12);
    out[IDX_OFF + blk * 64 + t] = (float)cw;
    cw_s[t] = cw;
    double v = dmin;
    v += __shfl_down(v, 32);
    v += __shfl_down(v, 16);
    v += __shfl_down(v, 8);
    v += __shfl_down(v, 4);
    v += __shfl_down(v, 2);
    v += __shfl_down(v, 1);
    if (t == 0)
      atomicAdd(out, (float)(1.25 * v / 16777216.0));
  }
  __syncthreads();

  // ---- quant: two 32-row transpose passes through qs (reuses As) ----
  float* qs = (float*)As;   // [256 d][33] = 33792 B
  const int rw = t >> 3, li = t & 7;
#pragma unroll 1
  for (int half = 0; half < 2; ++half) {
    const int cw = cw_s[half * 32 + rw];
    const float* wr = wn + (size_t)cw * EMB_DIM;
#pragma unroll
    for (int k = 0; k < 8; ++k) {
      const int d0 = k * 32 + li * 4;
      const float4 wv = *(const float4*)&wr[d0];
      qs[(d0 + 0) * 33 + rw] = wv.x;
      qs[(d0 + 1) * 33 + rw] = wv.y;
      qs[(d0 + 2) * 33 + rw] = wv.z;
      qs[(d0 + 3) * 33 + rw] = wv.w;
    }
    __syncthreads();
    {
      const int hw4 = (t & 7) * 4, dbase = t >> 3;   // 32 d-groups of 8
      float* qout = out + QUANT_OFF + (size_t)b * (EMB_DIM * HW) + hw0 + half * 32;
#pragma unroll
      for (int jj = 0; jj < 8; ++jj) {
        const int d = jj * 32 + dbase;
        float4 v4;
        v4.x = qs[d * 33 + hw4 + 0];
        v4.y = qs[d * 33 + hw4 + 1];
        v4.z = qs[d * 33 + hw4 + 2];
        v4.w = qs[d * 33 + hw4 + 3];
        *(float4*)&qout[(size_t)d * HW + hw4] = v4;
      }
    }
    __syncthreads();
  }
}

extern "C" void kernel_launch(void* const* d_in, const int* in_sizes, int n_in,
                              void* d_out, int out_size, void* d_ws, size_t ws_size,
                              hipStream_t stream) {
  const float* x = (const float*)d_in[0];   // [64,256,32,32]
  const float* w = (const float*)d_in[1];   // [1024,256]
  float* out = (float*)d_out;               // [1 + 16777216 + 65536] f32

  char* ws = (char*)d_ws;
  float*     wn   = (float*)ws;                                // 1 MB
  _Float16*  wh2  = (_Float16*)(ws + 1048576);                 // 512 KB (swizzled)
  double*    rinv = (double*)(ws + 1048576 + 524288);          // 8 KB

  hipMemsetAsync(d_out, 0, sizeof(float), stream);   // zero loss accumulator
  hipLaunchKernelGGL(k_norm_w, dim3(NUM_EMB), dim3(256), 0, stream, w, wn, wh2, rinv);
  hipLaunchKernelGGL(k_fused, dim3(N_ROWS / 64), dim3(256), 0, stream, x, wh2, w, wn, rinv, out);
}